// Round 1
// baseline (522.115 us; speedup 1.0000x reference)
//
#include <hip/hip_runtime.h>

#define N_ITEMS 500000
#define EMBED 64
#define BATCH 1024
#define TILE 128
#define NCHUNK ((N_ITEMS + TILE - 1) / TILE)   // 3907
#define LDK 72                                  // padded LDS row stride (bf16 elems)

typedef __attribute__((ext_vector_type(8))) __bf16 bf16x8;
typedef __attribute__((ext_vector_type(4))) float f32x4;

__device__ __forceinline__ unsigned f2bf(float x) {
  union { float f; unsigned u; } v; v.f = x;
  return (v.u + 0x7FFFu + ((v.u >> 16) & 1u)) >> 16;   // RNE fp32 -> bf16 bits
}
__device__ __forceinline__ float bf2f(unsigned b) {
  union { unsigned u; float f; } v; v.u = b << 16;
  return v.f;
}

// convert 8 floats -> 8 hi-bf16 (packed uint4) + 8 lo-bf16 (packed uint4)
__device__ __forceinline__ void cvt8(const float* f, uint4& H, uint4& L) {
  unsigned h[8], l[8];
#pragma unroll
  for (int k = 0; k < 8; ++k) {
    float x = f[k];
    unsigned hb = f2bf(x);
    float r = x - bf2f(hb);   // exact (Sterbenz-adjacent)
    h[k] = hb;
    l[k] = f2bf(r);
  }
  H = make_uint4(h[0] | (h[1] << 16), h[2] | (h[3] << 16),
                 h[4] | (h[5] << 16), h[6] | (h[7] << 16));
  L = make_uint4(l[0] | (l[1] << 16), l[2] | (l[3] << 16),
                 l[4] | (l[5] << 16), l[6] | (l[7] << 16));
}

// stage 32 consecutive floats of one row into hi/lo LDS (32 bf16 each)
__device__ __forceinline__ void stage_row(const float* src, unsigned short* dstH,
                                          unsigned short* dstL) {
#pragma unroll
  for (int i = 0; i < 4; ++i) {
    f32x4 a = *(const f32x4*)(src + i * 8);
    f32x4 b = *(const f32x4*)(src + i * 8 + 4);
    float buf[8] = {a[0], a[1], a[2], a[3], b[0], b[1], b[2], b[3]};
    uint4 H, L;
    cvt8(buf, H, L);
    *(uint4*)(dstH + i * 8) = H;
    *(uint4*)(dstL + i * 8) = L;
  }
}

__global__ __launch_bounds__(256, 2)
void sim_kernel(const float* __restrict__ emb, const int* __restrict__ idx,
                unsigned long long* __restrict__ best, int nbj) {
  __shared__ unsigned short Ah[TILE * LDK];
  __shared__ unsigned short Al[TILE * LDK];
  __shared__ unsigned short Bh[TILE * LDK];
  __shared__ unsigned short Bl[TILE * LDK];
  __shared__ int sidx[TILE];

  const int tid  = threadIdx.x;
  const int lane = tid & 63;
  const int wv   = tid >> 6;
  const int wm   = wv >> 1;      // 2x2 wave grid, 64x64 per wave
  const int wn   = wv & 1;
  const int mt   = blockIdx.x & 7;        // 8 M-tiles cover 1024 queries
  const int jg   = blockIdx.x >> 3;       // item-chunk group
  const int m0   = mt * TILE;

  const int lrow = tid >> 1;   // 0..127: tile row this thread stages
  const int half = tid & 1;    // which 32-float half of the row
  const int c0   = half * 32;

  // ---- stage A (gathered query rows), hi+lo ----
  {
    int q = m0 + lrow;
    int row = idx[q] - 1;
    if (row < 0) row += N_ITEMS;       // numpy negative-index wrap
    if (half == 0) sidx[lrow] = row;
    stage_row(emb + (size_t)row * EMBED + c0,
              Ah + lrow * LDK + c0, Al + lrow * LDK + c0);
  }
  __syncthreads();

  int self_[16];
  float bs[16];
  unsigned bj[16];
#pragma unroll
  for (int am = 0; am < 4; ++am)
#pragma unroll
    for (int r = 0; r < 4; ++r) {
      int sl = am * 4 + r;
      self_[sl] = sidx[wm * 64 + am * 16 + ((lane >> 4) << 2) + r];
      bs[sl] = -3.4e38f;
      bj[sl] = 0xFFFFFFFFu;
    }

  f32x4 acc[4][4];

  for (int ch = jg; ch < NCHUNK; ch += nbj) {
    const int j0 = ch * TILE;
    __syncthreads();   // protect B LDS from previous iteration readers
    {
      int jr = j0 + lrow;
      unsigned short* dh = Bh + lrow * LDK + c0;
      unsigned short* dl = Bl + lrow * LDK + c0;
      if (jr < N_ITEMS) {
        stage_row(emb + (size_t)jr * EMBED + c0, dh, dl);
      } else {
        uint4 z = make_uint4(0, 0, 0, 0);
#pragma unroll
        for (int i = 0; i < 4; ++i) {
          *(uint4*)(dh + i * 8) = z;
          *(uint4*)(dl + i * 8) = z;
        }
      }
    }
    __syncthreads();

    f32x4 zero = {0.f, 0.f, 0.f, 0.f};
#pragma unroll
    for (int am = 0; am < 4; ++am)
#pragma unroll
      for (int bn = 0; bn < 4; ++bn)
        acc[am][bn] = zero;

    // 3-term split-bf16: hi*hi + lo*hi + hi*lo  (error ~2^-18 scale)
#pragma unroll
    for (int t = 0; t < 3; ++t) {
      const unsigned short* As = (t == 1) ? Al : Ah;
      const unsigned short* Bs = (t == 2) ? Bl : Bh;
#pragma unroll
      for (int ks = 0; ks < 2; ++ks) {
        const int koff = ks * 32 + ((lane >> 4) << 3);
        bf16x8 af[4], bfr[4];
#pragma unroll
        for (int am = 0; am < 4; ++am)
          af[am] = *(const bf16x8*)(As + (wm * 64 + am * 16 + (lane & 15)) * LDK + koff);
#pragma unroll
        for (int bn = 0; bn < 4; ++bn)
          bfr[bn] = *(const bf16x8*)(Bs + (wn * 64 + bn * 16 + (lane & 15)) * LDK + koff);
#pragma unroll
        for (int am = 0; am < 4; ++am)
#pragma unroll
          for (int bn = 0; bn < 4; ++bn)
            acc[am][bn] = __builtin_amdgcn_mfma_f32_16x16x32_bf16(
                af[am], bfr[bn], acc[am][bn], 0, 0, 0);
      }
    }

    // running per-thread max/argmax (C layout: col=lane&15, row=(lane>>4)*4+reg)
#pragma unroll
    for (int bn = 0; bn < 4; ++bn) {
      const int jc = j0 + wn * 64 + bn * 16 + (lane & 15);
      const bool jok = jc < N_ITEMS;
#pragma unroll
      for (int am = 0; am < 4; ++am)
#pragma unroll
        for (int r = 0; r < 4; ++r) {
          const int sl = am * 4 + r;
          float v = acc[am][bn][r];
          v = (jok && jc != self_[sl]) ? v : -3.4e38f;
          if (v > bs[sl]) { bs[sl] = v; bj[sl] = (unsigned)jc; }
        }
    }
  }

  // ---- epilogue: per-row reduce over the 32 column-groups, then atomic ----
  __syncthreads();
  float* Ss    = (float*)Bh;     // 128*32*4 = 16 KB <= 18 KB
  unsigned* Sj = (unsigned*)Ah;  // 16 KB <= 18 KB
  const int cg = wn * 16 + (lane & 15);
#pragma unroll
  for (int am = 0; am < 4; ++am)
#pragma unroll
    for (int r = 0; r < 4; ++r) {
      const int sl = am * 4 + r;
      const int rl = wm * 64 + am * 16 + ((lane >> 4) << 2) + r;
      Ss[rl * 32 + cg] = bs[sl];
      Sj[rl * 32 + cg] = bj[sl];
    }
  __syncthreads();
  if (tid < TILE) {
    float b = -3.4e38f;
    unsigned j = 0xFFFFFFFFu;
    for (int c = 0; c < 32; ++c) {
      float s = Ss[tid * 32 + c];
      unsigned jj = Sj[tid * 32 + c];
      if (s > b || (s == b && jj < j)) { b = s; j = jj; }
    }
    // order-preserving float->uint map; smaller j wins ties via ~j in low bits
    union { float f; int i; unsigned u; } cv; cv.f = b;
    unsigned mu = (cv.i < 0) ? ~cv.u : (cv.u | 0x80000000u);
    unsigned long long key =
        ((unsigned long long)mu << 32) | (unsigned long long)(0xFFFFFFFFu - j);
    atomicMax(best + m0 + tid, key);
  }
}

__global__ void extract_kernel(const unsigned long long* __restrict__ best,
                               const float* __restrict__ mn,
                               const float* __restrict__ mx,
                               float* __restrict__ out) {
  int t = blockIdx.x * blockDim.x + threadIdx.x;
  if (t >= BATCH) return;
  unsigned long long k = best[t];
  unsigned mu = (unsigned)(k >> 32);
  unsigned j  = 0xFFFFFFFFu - (unsigned)(k & 0xFFFFFFFFull);
  union { unsigned u; float f; } cv;
  cv.u = (mu & 0x80000000u) ? (mu & 0x7FFFFFFFu) : ~mu;
  float s = cv.f;
  float lo = mn[0], hi = mx[0];
  out[t] = (float)(j + 1);                    // indices = argmax + 1
  out[BATCH + t] = (s - lo) / (hi - lo);      // normalized score
}

extern "C" void kernel_launch(void* const* d_in, const int* in_sizes, int n_in,
                              void* d_out, int out_size, void* d_ws, size_t ws_size,
                              hipStream_t stream) {
  const float* emb = (const float*)d_in[0];
  const int* idx   = (const int*)d_in[1];
  const float* mn  = (const float*)d_in[2];
  const float* mx  = (const float*)d_in[3];
  unsigned long long* best = (unsigned long long*)d_ws;

  hipMemsetAsync(d_ws, 0, BATCH * sizeof(unsigned long long), stream);

  const int nbj = 512;                 // chunk-groups; 8*512 = 4096 blocks
  sim_kernel<<<dim3(8 * nbj), dim3(256), 0, stream>>>(emb, idx, best, nbj);
  extract_kernel<<<dim3((BATCH + 255) / 256), dim3(256), 0, stream>>>(
      best, mn, mx, (float*)d_out);
}